// Round 10
// baseline (427.197 us; speedup 1.0000x reference)
//
#include <hip/hip_runtime.h>
#include <hip/hip_bf16.h>
#include <stdint.h>
#include <stddef.h>

typedef short v8s __attribute__((ext_vector_type(8)));
typedef short v4s __attribute__((ext_vector_type(4)));
typedef float v4f __attribute__((ext_vector_type(4)));
typedef float v16f __attribute__((ext_vector_type(16)));
typedef unsigned long long u64;

#define STEPSZ 0.01f
#define MFMA16(a, b, c) __builtin_amdgcn_mfma_f32_16x16x32_bf16((a), (b), (c), 0, 0, 0)
#define MFMA32(a, b, c) __builtin_amdgcn_mfma_f32_32x32x16_bf16((a), (b), (c), 0, 0, 0)

/* workspace layout (bytes) */
#define OFF_ATT 0u        /* bf16 [4096][256] 2 MB : AtT rows (n*8+j)=A[m,n,j]*rev[j] over m */
#define OFF_GRT 2097152u  /* bf16 [4096][512] 4 MB : GramT rows (n*8+g) over n' */
#define OFF_CT  6291456u  /* f32  [512][512]  1 MB : cT rows (b*8+k) over n */
#define OFF_YB  7340032u  /* bf16 [512][256] 256 KB: y blades rows (b*8+i) over m */
#define OFF_XB0 7602176u  /* bf16 [512][512] 512 KB: x operand buffer 0 */
#define OFF_XB1 8126464u  /* bf16 [512][512] 512 KB: x operand buffer 1 */
#define OFF_BAR 8650752u  /* int  [256]             : per-block iteration flags */

__device__ __forceinline__ int csign(int i, int j) {  /* reorder parity of e_i * e_j */
  return (__popc((i >> 1) & j) + __popc((i >> 2) & j)) & 1;
}

/* ---- agent-scope (L3 coherence point) ops: correct under ANY block->XCD map */
__device__ __forceinline__ v8s aload16(const void* p) {
  u64 lo = __hip_atomic_load((const u64*)p, __ATOMIC_RELAXED, __HIP_MEMORY_SCOPE_AGENT);
  u64 hi = __hip_atomic_load((const u64*)p + 1, __ATOMIC_RELAXED, __HIP_MEMORY_SCOPE_AGENT);
  union { u64 u; v4s s; } a, b;
  a.u = lo; b.u = hi;
  return __builtin_shufflevector(a.s, b.s, 0, 1, 2, 3, 4, 5, 6, 7);
}

/* prep: AtT + yb + flag zero in one launch */
__global__ void prep_all(const float* __restrict__ A, const float* __restrict__ y,
                         __hip_bfloat16* __restrict__ AtT, __hip_bfloat16* __restrict__ yb,
                         int* __restrict__ bars) {
  const int n = blockIdx.x;   // 512
  const int m = threadIdx.x;  // 256
  const float* ap = A + ((size_t)m * 512 + n) * 8;
  const float rev[8] = {1.f, 1.f, 1.f, -1.f, 1.f, -1.f, -1.f, -1.f};
#pragma unroll
  for (int j = 0; j < 8; ++j)
    AtT[(size_t)(n * 8 + j) * 256 + m] = __float2bfloat16(ap[j] * rev[j]);
  yb[(size_t)n * 256 + m] = __float2bfloat16(y[((size_t)(n >> 3) * 256 + m) * 8 + (n & 7)]);
  if (n == 0)
    __hip_atomic_store(bars + m, 0, __ATOMIC_RELAXED, __HIP_MEMORY_SCOPE_AGENT);
}

/* c[b,n,k] = (y * rev(A))[k]  (verified structure; K-loop fully unrolled so the
 * compiler hoists fragment loads ahead of the MFMA chain -> one exposed latency) */
__global__ __launch_bounds__(256) void c_kernel(const __hip_bfloat16* __restrict__ yb,
                                                const __hip_bfloat16* __restrict__ AtT,
                                                float* __restrict__ cT) {
  __shared__ float Pt[64 * 66];
  const int tid = threadIdx.x;
  const int wave = tid >> 6, lane = tid & 63;
  const int fr = lane & 15, fq = lane >> 4;
  const int wr = (wave >> 1) * 32, wc = (wave & 1) * 32;
  const int r0 = blockIdx.y * 64, c0 = blockIdx.x * 64;
  v4f acc[2][2] = {};
#pragma unroll
  for (int kk = 0; kk < 8; ++kk) {
    const int k0 = kk * 32;
    v8s a0 = *(const v8s*)(yb + (size_t)(r0 + wr + fr) * 256 + k0 + fq * 8);
    v8s a1 = *(const v8s*)(yb + (size_t)(r0 + wr + 16 + fr) * 256 + k0 + fq * 8);
    v8s b0 = *(const v8s*)(AtT + (size_t)(c0 + wc + fr) * 256 + k0 + fq * 8);
    v8s b1 = *(const v8s*)(AtT + (size_t)(c0 + wc + 16 + fr) * 256 + k0 + fq * 8);
    acc[0][0] = MFMA16(a0, b0, acc[0][0]);
    acc[0][1] = MFMA16(a0, b1, acc[0][1]);
    acc[1][0] = MFMA16(a1, b0, acc[1][0]);
    acc[1][1] = MFMA16(a1, b1, acc[1][1]);
  }
#pragma unroll
  for (int r = 0; r < 2; ++r)
#pragma unroll
    for (int c = 0; c < 2; ++c)
#pragma unroll
      for (int v = 0; v < 4; ++v)
        Pt[(wr + r * 16 + fq * 4 + v) * 66 + wc + c * 16 + fr] = acc[r][c][v];
  __syncthreads();
  for (int o = tid; o < 512; o += 256) {
    const int bl = o >> 6, k = (o >> 3) & 7, nl = o & 7;
    float s = 0.f;
#pragma unroll
    for (int j = 0; j < 8; ++j) {
      const int i = k ^ j;
      const float p = Pt[(bl * 8 + i) * 66 + nl * 8 + j];
      s += csign(i, j) ? -p : p;
    }
    cT[((size_t)((blockIdx.y * 8 + bl) * 8 + k)) * 512 + blockIdx.x * 8 + nl] = s;
  }
}

/* GramT[(n*8+g)][n'] = (A[:,n'] * rev(A[:,n]))[g]  (verified structure; unrolled) */
__global__ __launch_bounds__(256) void gram_kernel(const __hip_bfloat16* __restrict__ AtT,
                                                   __hip_bfloat16* __restrict__ GrT) {
  __shared__ float Pt[64 * 66];
  const int tid = threadIdx.x;
  const int wave = tid >> 6, lane = tid & 63;
  const int fr = lane & 15, fq = lane >> 4;
  const int wr = (wave >> 1) * 32, wc = (wave & 1) * 32;
  const int r0 = blockIdx.y * 64, c0 = blockIdx.x * 64;
  v4f acc[2][2] = {};
#pragma unroll
  for (int kk = 0; kk < 8; ++kk) {
    const int k0 = kk * 32;
    v8s a0 = *(const v8s*)(AtT + (size_t)(r0 + wr + fr) * 256 + k0 + fq * 8);
    v8s a1 = *(const v8s*)(AtT + (size_t)(r0 + wr + 16 + fr) * 256 + k0 + fq * 8);
    v8s b0 = *(const v8s*)(AtT + (size_t)(c0 + wc + fr) * 256 + k0 + fq * 8);
    v8s b1 = *(const v8s*)(AtT + (size_t)(c0 + wc + 16 + fr) * 256 + k0 + fq * 8);
    acc[0][0] = MFMA16(a0, b0, acc[0][0]);
    acc[0][1] = MFMA16(a0, b1, acc[0][1]);
    acc[1][0] = MFMA16(a1, b0, acc[1][0]);
    acc[1][1] = MFMA16(a1, b1, acc[1][1]);
  }
#pragma unroll
  for (int r = 0; r < 2; ++r)
#pragma unroll
    for (int c = 0; c < 2; ++c)
#pragma unroll
      for (int v = 0; v < 4; ++v)
        Pt[(wr + r * 16 + fq * 4 + v) * 66 + wc + c * 16 + fr] = acc[r][c][v];
  __syncthreads();
  const float rev[8] = {1.f, 1.f, 1.f, -1.f, 1.f, -1.f, -1.f, -1.f};
  for (int o = tid; o < 512; o += 256) {
    const int nl = o >> 6, g = (o >> 3) & 7, npl = o & 7;
    float s = 0.f;
#pragma unroll
    for (int j = 0; j < 8; ++j) {
      const int i = g ^ j;
      const float sg = (csign(i, j) ? -1.f : 1.f) * rev[i];
      s += sg * Pt[(npl * 8 + i) * 66 + nl * 8 + j];
    }
    GrT[((size_t)((blockIdx.x * 8 + nl) * 8 + g)) * 512 + blockIdx.y * 8 + npl] =
        __float2bfloat16(s);
  }
}

/* Persistent kernel (r8-verified structure). Cluster = 16 blocks:
 * cl = (bid&7)*2 + (bid>>7), w = (bid>>3)&15; cluster owns 4 batches = 32 rows.
 * Block w owns n in [w*32,+32) -> 256 GramT rows in VGPRs (8 waves x 128 regs).
 * mfma 32x32x16, K=512, x staged in LDS. One flag barrier per iteration.
 * NEW vs r8: distributed poll -- each thread polls exactly the 4 producer
 * slots {scol>>2,+4,+8,+12} whose x-columns it stages (chunk c covers cols
 * [c*8,c*8+8) -> producer w=c>>2), so the post-poll __syncthreads is removed. */
__global__ __launch_bounds__(512, 2) void ista_persist(
    const __hip_bfloat16* __restrict__ GrT, const float* __restrict__ cT,
    __hip_bfloat16* __restrict__ xb0, __hip_bfloat16* __restrict__ xb1,
    float* __restrict__ out, int* __restrict__ bars) {
  /* [0,32K) x-stage [32 rows][1024 B] (chunk c at slot c^(row&15)) |
   * [32K,+34304) Pt f32 [32][pitch 268] */
  __shared__ __align__(16) char lds[32768 + 34304];
  float* const Pt = (float*)(lds + 32768);

  const int tid = threadIdx.x;
  const int wave = tid >> 6, lane = tid & 63;
  const int lr = lane & 31, lh = lane >> 5;  // tile row, k-half
  const int cl = (blockIdx.x & 7) * 2 + (blockIdx.x >> 7);
  const int w = (blockIdx.x >> 3) & 15;
  const int rowbase = cl * 32;
  int* const flags = bars + cl * 16;

  /* persistent B in registers: GramT rows [w*256 + wave*32 + lr], all K */
  v8s B[32];
  {
    const __hip_bfloat16* gB = GrT + (size_t)(w * 256 + wave * 32 + lr) * 512 + lh * 8;
#pragma unroll
    for (int kt = 0; kt < 32; ++kt) B[kt] = *(const v8s*)(gB + kt * 16);
  }

  /* x-stage addressing */
  const int srow = tid >> 4, scol = tid & 15;
  /* epilogue mapping: 512 threads x 2 outputs (n = en*2 + {0,1}) */
  const int eb = tid >> 7, ek = (tid >> 4) & 7, en = tid & 15;
  const int xrow = rowbase + eb * 8 + ek;  // next-iter A row (b,i=k)
  const float thr = (ek == 0) ? 0.f : ((ek == 7) ? 0.002f : 0.001f);
  const float* const crow = cT + (size_t)(xrow)*512 + w * 32 + en * 2;
  float* const orow = out + ((size_t)(cl * 4 + eb) * 512 + w * 32 + en * 2) * 8 + ek;
  const int p0 = scol >> 2;  // this thread's 4 producer slots: p0, p0+4, p0+8, p0+12
  float xreg[2] = {0.f, 0.f};

  for (int it = 0; it < 50; ++it) {
    if (it > 0) {
      /* distributed poll: wait for this thread's 4 producers to post iter it */
      for (;;) {
        int f0 = __hip_atomic_load(flags + p0, __ATOMIC_RELAXED, __HIP_MEMORY_SCOPE_AGENT);
        int f1 = __hip_atomic_load(flags + p0 + 4, __ATOMIC_RELAXED, __HIP_MEMORY_SCOPE_AGENT);
        int f2 = __hip_atomic_load(flags + p0 + 8, __ATOMIC_RELAXED, __HIP_MEMORY_SCOPE_AGENT);
        int f3 = __hip_atomic_load(flags + p0 + 12, __ATOMIC_RELAXED, __HIP_MEMORY_SCOPE_AGENT);
        if (f0 >= it && f1 >= it && f2 >= it && f3 >= it) break;
        __builtin_amdgcn_s_sleep(1);
      }
      asm volatile("" ::: "memory");
      /* stage x_(it): rows x 1 KB into LDS (XOR-16 swizzle); the 4 chunks this
       * thread loads are exactly the columns its 4 polled producers wrote */
      {
        const __hip_bfloat16* xr = (it & 1) ? xb1 : xb0;
        const char* g = (const char*)(xr + (size_t)(rowbase + srow) * 512) + scol * 16;
#pragma unroll
        for (int q = 0; q < 4; ++q) {
          const int c = scol + q * 16;
          v8s v = aload16(g + q * 256);
          *(v8s*)(lds + srow * 1024 + ((c ^ (srow & 15)) << 4)) = v;
        }
      }
      __syncthreads();
      /* K-loop: 32 MFMAs, B from regs, A from LDS (2-way swizzle = free) */
      v16f acc = {};
#pragma unroll
      for (int kt = 0; kt < 32; ++kt) {
        const int cidx = kt * 2 + lh;
        v8s a = *(const v8s*)(lds + lr * 1024 + ((cidx ^ (lr & 15)) << 4));
        acc = MFMA32(a, B[kt], acc);
      }
      /* dump P tile: C/D layout col=lane&31, row=(r&3)+8*(r>>2)+4*(lane>>5) */
#pragma unroll
      for (int r = 0; r < 16; ++r)
        Pt[((r & 3) + 8 * (r >> 2) + 4 * lh) * 268 + wave * 32 + lr] = acc[r];
    }
    __syncthreads();
    /* epilogue: blade recombine + ISTA update + x publish */
    {
      __hip_bfloat16* const xw = (it & 1) ? xb0 : xb1;
      unsigned int pack = 0;
#pragma unroll
      for (int c = 0; c < 2; ++c) {
        float s = 0.f;
        if (it > 0) {
          const int n = en * 2 + c;
#pragma unroll
          for (int j = 0; j < 8; ++j) {
            const int i = ek ^ j;
            const float p = Pt[(eb * 8 + i) * 268 + n * 8 + j];
            s += csign(i, j) ? -p : p;
          }
        }
        float xv = xreg[c] - STEPSZ * (s - crow[c]);
        const float ax = fabsf(xv) - thr;
        xv = (ax > 0.f) ? copysignf(ax, xv) : 0.f;
        xreg[c] = xv;
        __hip_bfloat16 h = __float2bfloat16(xv);
        unsigned short bits;
        __builtin_memcpy(&bits, &h, 2);
        pack |= ((unsigned int)bits) << (c * 16);
        if (it == 49) orow[c * 8] = xv;
      }
      __hip_atomic_store((unsigned int*)(xw + (size_t)xrow * 512 + w * 32 + en * 2),
                         pack, __ATOMIC_RELAXED, __HIP_MEMORY_SCOPE_AGENT);
    }
    __syncthreads();  /* per-wave vmcnt(0) drain -> all publishes globally visible */
    if (tid == 0 && it < 49)
      __hip_atomic_store(flags + w, it + 1, __ATOMIC_RELAXED, __HIP_MEMORY_SCOPE_AGENT);
  }
}

extern "C" void kernel_launch(void* const* d_in, const int* in_sizes, int n_in,
                              void* d_out, int out_size, void* d_ws, size_t ws_size,
                              hipStream_t stream) {
  (void)in_sizes; (void)n_in; (void)out_size; (void)ws_size;
  const float* y = (const float*)d_in[0];
  const float* A = (const float*)d_in[1];
  float* out = (float*)d_out;
  char* ws = (char*)d_ws;

  __hip_bfloat16* AtT = (__hip_bfloat16*)(ws + OFF_ATT);
  __hip_bfloat16* GrT = (__hip_bfloat16*)(ws + OFF_GRT);
  float* cT = (float*)(ws + OFF_CT);
  __hip_bfloat16* yb = (__hip_bfloat16*)(ws + OFF_YB);
  __hip_bfloat16* xb0 = (__hip_bfloat16*)(ws + OFF_XB0);
  __hip_bfloat16* xb1 = (__hip_bfloat16*)(ws + OFF_XB1);
  int* bars = (int*)(ws + OFF_BAR);

  prep_all<<<512, 256, 0, stream>>>(A, y, AtT, yb, bars);
  c_kernel<<<dim3(64, 8), 256, 0, stream>>>(yb, AtT, cT);
  gram_kernel<<<dim3(64, 64), 256, 0, stream>>>(AtT, GrT);

  ista_persist<<<256, 512, 0, stream>>>(GrT, cT, xb0, xb1, out, bars);
}